// Round 2
// baseline (101.880 us; speedup 1.0000x reference)
//
#include <hip/hip_runtime.h>

typedef float f32x4 __attribute__((ext_vector_type(4)));

#define ZD      128      // feature dim (bytes per fp8 row, too)
#define BT      128      // block tile (128x128, 64x64 per wave)
#define D2_CUT  60.0f    // exact-path cutoff: exp(-30)~9e-14
#define D2_TRIG 70.0f    // trigger: fp8 dot err <= ~+-3 on d2 => skip implies
                         // true d2 >= 70-6 > D2_CUT (12-sigma data margin)

// ---------------------------------------------------------------------------
// Kernel A (verbatim from verified R9): 256 blocks x 32 rows. ||z_i||^2
// (fp32 exact), per-32-row min, z -> fp8 e4m3 (HW cvt_pk). Block 0 / wave 2:
// class counts over all s, analytic diagonal, out[0] = diag*scale.
// ---------------------------------------------------------------------------
__global__ __launch_bounds__(256) void dep_prep(
    const float* __restrict__ z, const int* __restrict__ s,
    float* __restrict__ sq, float* __restrict__ sqmin,
    unsigned char* __restrict__ zb8, float* __restrict__ pvals,
    const float* __restrict__ norm, float* __restrict__ out, int N)
{
    __shared__ float part[32][33];
    const int tid  = threadIdx.x;
    const int wave = tid >> 6, lane = tid & 63;
    const int half = lane >> 5, c = lane & 31;
    const int r0   = blockIdx.x * 32;

    if (blockIdx.x == 0 && wave == 2) {
        int c0 = 0, c1 = 0, c2 = 0, c3 = 0;
        for (int it = lane; it < N / 4; it += 64) {
            int4 v = ((const int4*)s)[it];
            c0 += (v.x == 0) + (v.y == 0) + (v.z == 0) + (v.w == 0);
            c1 += (v.x == 1) + (v.y == 1) + (v.z == 1) + (v.w == 1);
            c2 += (v.x == 2) + (v.y == 2) + (v.z == 2) + (v.w == 2);
            c3 += (v.x == 3) + (v.y == 3) + (v.z == 3) + (v.w == 3);
        }
        #pragma unroll
        for (int off = 1; off < 64; off <<= 1) {
            c0 += __shfl_xor(c0, off, 64);
            c1 += __shfl_xor(c1, off, 64);
            c2 += __shfl_xor(c2, off, 64);
            c3 += __shfl_xor(c3, off, 64);
        }
        if (lane == 0) {
            const double n = (double)N;
            const double p0 = c0 / n, p1 = c1 / n, p2 = c2 / n, p3 = c3 / n;
            const double sump2 = p0*p0 + p1*p1 + p2*p2 + p3*p3;
            const double scale = (1.0 - exp(-1.0)) / ((double)norm[0] * n * n);
            pvals[0] = (float)p0; pvals[1] = (float)p1;
            pvals[2] = (float)p2; pvals[3] = (float)p3;
            pvals[4] = (float)sump2;
            pvals[5] = (float)scale;
            const double c2sum = (double)c0*c0 + (double)c1*c1
                               + (double)c2*c2 + (double)c3*c3;
            const double diag = n - c2sum / n;   // K_z[i,i] = 1 analytically
            out[0] = (float)(diag * scale);
        }
    }

    #pragma unroll
    for (int i = 0; i < 4; ++i) {
        const int rloc = wave * 8 + i * 2 + half;
        const int r    = r0 + rloc;
        float4 v = ((const float4*)z)[r * 32 + c];
        int pk = __builtin_amdgcn_cvt_pk_fp8_f32(v.x, v.y, 0, false);
        pk     = __builtin_amdgcn_cvt_pk_fp8_f32(v.z, v.w, pk, true);
        ((unsigned int*)zb8)[r * 32 + c] = (unsigned int)pk;
        part[rloc][c] = v.x*v.x + v.y*v.y + v.z*v.z + v.w*v.w;
    }
    __syncthreads();

    if (wave == 0 && lane < 32) {
        float sum = 0.f;
        #pragma unroll
        for (int k = 0; k < 32; ++k) sum += part[lane][k];   // conflict-free
        sq[r0 + lane] = sum;
        float mn = sum;
        #pragma unroll
        for (int off = 1; off < 32; off <<= 1)               // lanes 0..31
            mn = fminf(mn, __shfl_xor(mn, off, 64));
        if (lane == 0) sqmin[blockIdx.x] = mn;
    }
}

// ---------------------------------------------------------------------------
// Kernel B: one block per 128x128 upper-triangle tile (2080 blocks).
// ZERO LDS, ZERO barriers. The R9 swizzle algebra collapses: the LDS read
// LDS[row][((kc*2+(quad>>1)) ^ (l15&7))*16 + sub] with the global-side
// XOR-swizzled DMA is byte-identical to a direct global load of
//   zb8[row*128 + kc*32 + quad*8]
// (8 contiguous bytes = one lane's fp8 A/B fragment for
// mfma_f32_16x16x32_fp8_fp8). zb8 is 1 MB -> fully L2-resident; a wave's
// 64 lanes cover 16 rows x 32 contiguous B; A-fragments are L1-reused by
// both wj waves and across kc. Waves are fully independent: no staging
// lockstep, no vmcnt(0) drain -- latency hidden by TLP (16 waves/CU).
// Epilogue identical to verified R9 (conservative d2 bound; rare exact path
// adds onto out[0] which prep pre-set to diag*scale).
// ---------------------------------------------------------------------------
__global__ __launch_bounds__(256, 4) void dep_pair(
    const unsigned char* __restrict__ zb8, const float* __restrict__ sq,
    const float* __restrict__ sqmin, const int* __restrict__ s,
    const float* __restrict__ pvals, float* __restrict__ out, int T)
{
    const int tid  = threadIdx.x;
    const int wave = tid >> 6, lane = tid & 63;

    // block-uniform triangle map t -> (ti <= tj)
    const int t = blockIdx.x;
    #define TRI_BASE(x) ((x) * T - ((x) * ((x) - 1)) / 2)
    double disc = (2.0 * T + 1.0) * (2.0 * T + 1.0) - 8.0 * (double)t;
    int ti = (int)((2.0 * T + 1.0 - sqrt(disc)) * 0.5);
    if (ti < 0) ti = 0;
    if (ti > T - 1) ti = T - 1;
    while (ti + 1 < T && TRI_BASE(ti + 1) <= t) ++ti;
    while (ti > 0 && TRI_BASE(ti) > t) --ti;
    const int tj = ti + (t - TRI_BASE(ti));
    #undef TRI_BASE

    const int i0 = ti * BT, j0 = tj * BT;
    const int wi = wave >> 1, wj = wave & 1;
    const int l15 = lane & 15, quad = lane >> 4;

    // per-lane fragment base pointers (8B-aligned)
    const unsigned char* Abase = zb8 + (size_t)(i0 + wi * 64 + l15) * ZD
                               + quad * 8;
    const unsigned char* Bbase = zb8 + (size_t)(j0 + wj * 64 + l15) * ZD
                               + quad * 8;

    f32x4 accv[4][4];
    #pragma unroll
    for (int a = 0; a < 4; ++a)
        #pragma unroll
        for (int b = 0; b < 4; ++b)
            accv[a][b] = (f32x4){0.f, 0.f, 0.f, 0.f};

    #pragma unroll
    for (int kc = 0; kc < 4; ++kc) {
        long af[4], bfr[4];
        #pragma unroll
        for (int it = 0; it < 4; ++it)
            af[it] = *(const long*)(Abase + (size_t)it * 16 * ZD + kc * 32);
        #pragma unroll
        for (int jt = 0; jt < 4; ++jt)
            bfr[jt] = *(const long*)(Bbase + (size_t)jt * 16 * ZD + kc * 32);
        #pragma unroll
        for (int it = 0; it < 4; ++it)
            #pragma unroll
            for (int jt = 0; jt < 4; ++jt)
                accv[it][jt] = __builtin_amdgcn_mfma_f32_16x16x32_fp8_fp8(
                    af[it], bfr[jt], accv[it][jt], 0, 0, 0);
    }

    // ---- fast epilogue: wave-max of dots vs conservative d2 lower bound ----
    float m = -1e30f;
    #pragma unroll
    for (int it = 0; it < 4; ++it)
        #pragma unroll
        for (int jt = 0; jt < 4; ++jt) {
            const f32x4 v = accv[it][jt];
            m = fmaxf(m, fmaxf(fmaxf(v[0], v[1]), fmaxf(v[2], v[3])));
        }
    #pragma unroll
    for (int off = 1; off < 64; off <<= 1)
        m = fmaxf(m, __shfl_xor(m, off, 64));

    const int gA = (i0 >> 5) + wi * 2;        // 32-row sqmin groups
    const int gB = (j0 >> 5) + wj * 2;
    const float sminA = fminf(sqmin[gA], sqmin[gA + 1]);
    const float sminB = fminf(sqmin[gB], sqmin[gB + 1]);
    const float bound = sminA + sminB - 2.0f * m;

    if (bound < D2_TRIG) {   // wave-uniform; diag quadrants + rare triggers
        const float p0 = pvals[0], p1 = pvals[1],
                    p2 = pvals[2], p3 = pvals[3];
        const float sump2 = pvals[4], scale = pvals[5];
        const float p[4] = {p0, p1, p2, p3};

        const int ibase = i0 + wi * 64, jbase = j0 + wj * 64;
        float sqj[4];
        #pragma unroll
        for (int jt = 0; jt < 4; ++jt) sqj[jt] = sq[jbase + jt * 16 + l15];

        float local = 0.f;
        #pragma unroll
        for (int it = 0; it < 4; ++it) {
            #pragma unroll
            for (int r = 0; r < 4; ++r) {
                const int i = ibase + it * 16 + quad * 4 + r;  // C/D row
                const float sqi = sq[i];
                #pragma unroll
                for (int jt = 0; jt < 4; ++jt) {
                    const int j = jbase + jt * 16 + l15;       // C/D col
                    float d2 = sqi + sqj[jt] - 2.0f * accv[it][jt][r];
                    d2 = fmaxf(d2, 0.0f);
                    if (d2 < D2_CUT && i != j) {
                        const int si = s[i], sj = s[j];
                        const float w = (si == sj ? 1.0f : 0.0f)
                                      - p[si] - p[sj] + sump2;
                        local += w * __expf(-0.5f * d2);
                    }
                }
            }
        }
        if (ti < tj) local *= 2.0f;   // off-diag tiles count both orders

        #pragma unroll
        for (int off = 32; off > 0; off >>= 1)
            local += __shfl_down(local, off, 64);
        if (lane == 0 && local != 0.0f)
            atomicAdd(out, local * scale);
    }
}

extern "C" void kernel_launch(void* const* d_in, const int* in_sizes, int n_in,
                              void* d_out, int out_size, void* d_ws, size_t ws_size,
                              hipStream_t stream)
{
    const float* z    = (const float*)d_in[0];
    const int*   s    = (const int*)d_in[1];
    const float* norm = (const float*)d_in[2];
    float* out = (float*)d_out;

    const int N = in_sizes[1];       // 8192
    const int T = N / BT;            // 64

    char* ws = (char*)d_ws;
    float*         pvals = (float*)ws;                        // 6 floats @0
    float*         sq    = (float*)(ws + 64);                 // N floats
    float*         sqmin = (float*)(ws + 64 + (size_t)N * 4); // N/32
    unsigned char* zb8   = (unsigned char*)(ws + 64 + (size_t)N * 4
                                            + (size_t)(N / 32) * 4); // 16B-aligned

    dep_prep<<<N / 32, 256, 0, stream>>>(z, s, sq, sqmin, zb8, pvals,
                                         norm, out, N);
    const int nblocks = T * (T + 1) / 2;   // 2080
    dep_pair<<<nblocks, 256, 0, stream>>>(zb8, sq, sqmin, s, pvals, out, T);
}

// Round 3
// 82.206 us; speedup vs baseline: 1.2393x; 1.2393x over previous
//
#include <hip/hip_runtime.h>

typedef float f32x4 __attribute__((ext_vector_type(4)));

#define ZD      128      // feature dim (bytes per fp8 row, too)
#define BT      128      // sub-tile (128x128, 64x64 per wave)
#define PAN     (BT * ZD)   // one fp8 panel = 16 KB
#define D2_CUT  60.0f    // exact-path cutoff: exp(-30)~9e-14
#define D2_TRIG 70.0f    // trigger: fp8 dot err <= ~+-3 on d2 => skip implies
                         // true d2 >= 70-6 > D2_CUT (12-sigma data margin)

// async global->LDS DMA, 16B per lane; LDS dest = wave-uniform base + lane*16
__device__ __forceinline__ void async_copy16(const unsigned char* g,
                                             unsigned char* l) {
    __builtin_amdgcn_global_load_lds(
        (const __attribute__((address_space(1))) unsigned int*)g,
        (__attribute__((address_space(3))) unsigned int*)l,
        16, 0, 0);
}

// ---------------------------------------------------------------------------
// Kernel A (verbatim from verified R9/R0): 256 blocks x 32 rows. ||z_i||^2
// (fp32 exact), per-32-row min, z -> fp8 e4m3 (HW cvt_pk). Block 0 / wave 2:
// class counts over all s, analytic diagonal, out[0] = diag*scale.
// ---------------------------------------------------------------------------
__global__ __launch_bounds__(256) void dep_prep(
    const float* __restrict__ z, const int* __restrict__ s,
    float* __restrict__ sq, float* __restrict__ sqmin,
    unsigned char* __restrict__ zb8, float* __restrict__ pvals,
    const float* __restrict__ norm, float* __restrict__ out, int N)
{
    __shared__ float part[32][33];
    const int tid  = threadIdx.x;
    const int wave = tid >> 6, lane = tid & 63;
    const int half = lane >> 5, c = lane & 31;
    const int r0   = blockIdx.x * 32;

    if (blockIdx.x == 0 && wave == 2) {
        int c0 = 0, c1 = 0, c2 = 0, c3 = 0;
        for (int it = lane; it < N / 4; it += 64) {
            int4 v = ((const int4*)s)[it];
            c0 += (v.x == 0) + (v.y == 0) + (v.z == 0) + (v.w == 0);
            c1 += (v.x == 1) + (v.y == 1) + (v.z == 1) + (v.w == 1);
            c2 += (v.x == 2) + (v.y == 2) + (v.z == 2) + (v.w == 2);
            c3 += (v.x == 3) + (v.y == 3) + (v.z == 3) + (v.w == 3);
        }
        #pragma unroll
        for (int off = 1; off < 64; off <<= 1) {
            c0 += __shfl_xor(c0, off, 64);
            c1 += __shfl_xor(c1, off, 64);
            c2 += __shfl_xor(c2, off, 64);
            c3 += __shfl_xor(c3, off, 64);
        }
        if (lane == 0) {
            const double n = (double)N;
            const double p0 = c0 / n, p1 = c1 / n, p2 = c2 / n, p3 = c3 / n;
            const double sump2 = p0*p0 + p1*p1 + p2*p2 + p3*p3;
            const double scale = (1.0 - exp(-1.0)) / ((double)norm[0] * n * n);
            pvals[0] = (float)p0; pvals[1] = (float)p1;
            pvals[2] = (float)p2; pvals[3] = (float)p3;
            pvals[4] = (float)sump2;
            pvals[5] = (float)scale;
            const double c2sum = (double)c0*c0 + (double)c1*c1
                               + (double)c2*c2 + (double)c3*c3;
            const double diag = n - c2sum / n;   // K_z[i,i] = 1 analytically
            out[0] = (float)(diag * scale);
        }
    }

    #pragma unroll
    for (int i = 0; i < 4; ++i) {
        const int rloc = wave * 8 + i * 2 + half;
        const int r    = r0 + rloc;
        float4 v = ((const float4*)z)[r * 32 + c];
        int pk = __builtin_amdgcn_cvt_pk_fp8_f32(v.x, v.y, 0, false);
        pk     = __builtin_amdgcn_cvt_pk_fp8_f32(v.z, v.w, pk, true);
        ((unsigned int*)zb8)[r * 32 + c] = (unsigned int)pk;
        part[rloc][c] = v.x*v.x + v.y*v.y + v.z*v.z + v.w*v.w;
    }
    __syncthreads();

    if (wave == 0 && lane < 32) {
        float sum = 0.f;
        #pragma unroll
        for (int k = 0; k < 32; ++k) sum += part[lane][k];   // conflict-free
        sq[r0 + lane] = sum;
        float mn = sum;
        #pragma unroll
        for (int off = 1; off < 32; off <<= 1)               // lanes 0..31
            mn = fminf(mn, __shfl_xor(mn, off, 64));
        if (lane == 0) sqmin[blockIdx.x] = mn;
    }
}

// ---------------------------------------------------------------------------
// Kernel B: 2x2 super-tiling. One block per 256x256 super-tile over the
// 32x32 super-triangle (528 blocks). Stages FOUR fp8 panels (A0,A1,B0,B1 =
// 64 KB LDS, 2 blocks/CU) with the verified R9 global-side XOR-swizzled DMA
// (LDS[row][ch] = G[row][ch ^ (row&7)], one vmcnt(0) drain), then computes
// the four 128x128 sub-tiles sequentially, reusing each panel twice.
// vs R0: staged bytes 66.5 -> 33.8 MB, drain events 2080 -> 528, MFMA per
// staged byte x2. Fragment ds_read + mfma_f32_16x16x32_fp8_fp8 + bound
// epilogue are verbatim from the verified R0 kernel (absmax-0 path).
// ---------------------------------------------------------------------------
__global__ __launch_bounds__(256, 2) void dep_pair(
    const unsigned char* __restrict__ zb8, const float* __restrict__ sq,
    const float* __restrict__ sqmin, const int* __restrict__ s,
    const float* __restrict__ pvals, float* __restrict__ out, int T)
{
    __shared__ unsigned char Apan[2 * PAN];   // 32KB (rows i0..i0+255)
    __shared__ unsigned char Bpan[2 * PAN];   // 32KB (rows j0..j0+255)

    const int tid  = threadIdx.x;
    const int wave = tid >> 6, lane = tid & 63;

    // block-uniform super-triangle map t -> (I <= J) over ST = T/2
    const int ST = T >> 1;
    const int t = blockIdx.x;
    #define TRI_BASE(x) ((x) * ST - ((x) * ((x) - 1)) / 2)
    double disc = (2.0 * ST + 1.0) * (2.0 * ST + 1.0) - 8.0 * (double)t;
    int I = (int)((2.0 * ST + 1.0 - sqrt(disc)) * 0.5);
    if (I < 0) I = 0;
    if (I > ST - 1) I = ST - 1;
    while (I + 1 < ST && TRI_BASE(I + 1) <= t) ++I;
    while (I > 0 && TRI_BASE(I) > t) --I;
    const int J = I + (t - TRI_BASE(I));
    #undef TRI_BASE

    const int i0 = I * 2 * BT, j0 = J * 2 * BT;   // super-tile origin rows
    const int wi = wave >> 1, wj = wave & 1;
    const int l15 = lane & 15, quad = lane >> 4;

    // async stage all four panels: per wave 16 DMAs of 1KB (8 rows each).
    // Panel-local layout identical to R0: LDS[row][c] = G[row][c ^ (row&7)]
    {
        const int rl  = lane >> 3;          // row within 8-row group (0..7)
        const int cch = lane & 7;           // dest 16B-chunk within row
        const int gch = cch ^ rl;           // source chunk (row&7 == rl)
        #pragma unroll
        for (int k = 0; k < 4; ++k) {
            const int r0i = (wave * 4 + k) * 8;        // wave-uniform 0..127
            const size_t go = (size_t)(r0i + rl) * ZD + (gch << 4);
            #pragma unroll
            for (int p = 0; p < 2; ++p) {
                async_copy16(zb8 + (size_t)(i0 + p * BT) * ZD + go,
                             Apan + p * PAN + r0i * ZD);
                async_copy16(zb8 + (size_t)(j0 + p * BT) * ZD + go,
                             Bpan + p * PAN + r0i * ZD);
            }
        }
    }
    __syncthreads();   // single vmcnt(0) drain for all 64KB

    const int sub = (quad & 1) * 8;         // 8B half within 16B chunk

    #pragma unroll 1
    for (int st = 0; st < 4; ++st) {        // sub-tile (a,b)
        const int a = st >> 1, b = st & 1;
        const int tis = 2 * I + a, tjs = 2 * J + b;
        if (tis > tjs) continue;            // block-uniform (only I==J, a>b)

        const unsigned char* Ap = Apan + a * PAN;
        const unsigned char* Bp = Bpan + b * PAN;
        const int i0s = i0 + a * BT, j0s = j0 + b * BT;

        f32x4 accv[4][4];
        #pragma unroll
        for (int x = 0; x < 4; ++x)
            #pragma unroll
            for (int y = 0; y < 4; ++y)
                accv[x][y] = (f32x4){0.f, 0.f, 0.f, 0.f};

        #pragma unroll
        for (int kc = 0; kc < 4; ++kc) {
            long af[4], bfr[4];
            // orig chunk = kc*2 + quad/2; row&7 == l15&7 for fragment rows
            const int ch = (kc * 2 + (quad >> 1)) ^ (l15 & 7);
            #pragma unroll
            for (int it = 0; it < 4; ++it) {
                const int row = wi * 64 + it * 16 + l15;
                af[it] = *(const long*)(Ap + row * ZD + (ch << 4) + sub);
            }
            #pragma unroll
            for (int jt = 0; jt < 4; ++jt) {
                const int row = wj * 64 + jt * 16 + l15;
                bfr[jt] = *(const long*)(Bp + row * ZD + (ch << 4) + sub);
            }
            #pragma unroll
            for (int it = 0; it < 4; ++it)
                #pragma unroll
                for (int jt = 0; jt < 4; ++jt)
                    accv[it][jt] = __builtin_amdgcn_mfma_f32_16x16x32_fp8_fp8(
                        af[it], bfr[jt], accv[it][jt], 0, 0, 0);
        }

        // ---- fast epilogue: wave-max dot vs conservative d2 lower bound ----
        float m = -1e30f;
        #pragma unroll
        for (int it = 0; it < 4; ++it)
            #pragma unroll
            for (int jt = 0; jt < 4; ++jt) {
                const f32x4 v = accv[it][jt];
                m = fmaxf(m, fmaxf(fmaxf(v[0], v[1]), fmaxf(v[2], v[3])));
            }
        #pragma unroll
        for (int off = 1; off < 64; off <<= 1)
            m = fmaxf(m, __shfl_xor(m, off, 64));

        const int gA = (i0s >> 5) + wi * 2;        // 32-row sqmin groups
        const int gB = (j0s >> 5) + wj * 2;
        const float sminA = fminf(sqmin[gA], sqmin[gA + 1]);
        const float sminB = fminf(sqmin[gB], sqmin[gB + 1]);
        const float bound = sminA + sminB - 2.0f * m;

        if (bound < D2_TRIG) {   // wave-uniform; diag quadrants + rare
            const float p0 = pvals[0], p1 = pvals[1],
                        p2 = pvals[2], p3 = pvals[3];
            const float sump2 = pvals[4], scale = pvals[5];
            const float p[4] = {p0, p1, p2, p3};

            const int ibase = i0s + wi * 64, jbase = j0s + wj * 64;
            float sqj[4];
            #pragma unroll
            for (int jt = 0; jt < 4; ++jt)
                sqj[jt] = sq[jbase + jt * 16 + l15];

            float local = 0.f;
            #pragma unroll
            for (int it = 0; it < 4; ++it) {
                #pragma unroll
                for (int r = 0; r < 4; ++r) {
                    const int i = ibase + it * 16 + quad * 4 + r;  // C/D row
                    const float sqi = sq[i];
                    #pragma unroll
                    for (int jt = 0; jt < 4; ++jt) {
                        const int j = jbase + jt * 16 + l15;       // C/D col
                        float d2 = sqi + sqj[jt] - 2.0f * accv[it][jt][r];
                        d2 = fmaxf(d2, 0.0f);
                        if (d2 < D2_CUT && i != j) {
                            const int si = s[i], sj = s[j];
                            const float w = (si == sj ? 1.0f : 0.0f)
                                          - p[si] - p[sj] + sump2;
                            local += w * __expf(-0.5f * d2);
                        }
                    }
                }
            }
            if (tis < tjs) local *= 2.0f;   // off-diag tiles: both orders

            #pragma unroll
            for (int off = 32; off > 0; off >>= 1)
                local += __shfl_down(local, off, 64);
            if (lane == 0 && local != 0.0f)
                atomicAdd(out, local * scale);
        }
    }
}

extern "C" void kernel_launch(void* const* d_in, const int* in_sizes, int n_in,
                              void* d_out, int out_size, void* d_ws, size_t ws_size,
                              hipStream_t stream)
{
    const float* z    = (const float*)d_in[0];
    const int*   s    = (const int*)d_in[1];
    const float* norm = (const float*)d_in[2];
    float* out = (float*)d_out;

    const int N = in_sizes[1];       // 8192
    const int T = N / BT;            // 64 sub-tiles, 32 super-tiles

    char* ws = (char*)d_ws;
    float*         pvals = (float*)ws;                        // 6 floats @0
    float*         sq    = (float*)(ws + 64);                 // N floats
    float*         sqmin = (float*)(ws + 64 + (size_t)N * 4); // N/32
    unsigned char* zb8   = (unsigned char*)(ws + 64 + (size_t)N * 4
                                            + (size_t)(N / 32) * 4); // 16B-aligned

    dep_prep<<<N / 32, 256, 0, stream>>>(z, s, sq, sqmin, zb8, pvals,
                                         norm, out, N);
    const int ST = T / 2;
    const int nblocks = ST * (ST + 1) / 2;   // 528
    dep_pair<<<nblocks, 256, 0, stream>>>(zb8, sq, sqmin, s, pvals, out, T);
}

// Round 4
// 79.922 us; speedup vs baseline: 1.2747x; 1.0286x over previous
//
#include <hip/hip_runtime.h>

typedef float f32x4 __attribute__((ext_vector_type(4)));

#define ZD      128      // feature dim (bytes per fp8 row, too)
#define BT      128      // sub-tile (128x128; 64x64 per wave-quadrant)
#define PAN     (BT * ZD)     // one 128-row fp8 panel = 16 KB
#define SPAN    (2 * PAN)     // one 256-row fp8 panel = 32 KB
#define D2_CUT  60.0f    // exact-path cutoff: exp(-30)~9e-14
#define D2_TRIG 70.0f    // trigger: fp8 dot err <= ~+-3 on d2 => skip implies
                         // true d2 >= 70-6 > D2_CUT (12-sigma data margin)

// async global->LDS DMA, 16B per lane; LDS dest = wave-uniform base + lane*16
__device__ __forceinline__ void async_copy16(const unsigned char* g,
                                             unsigned char* l) {
    __builtin_amdgcn_global_load_lds(
        (const __attribute__((address_space(1))) unsigned int*)g,
        (__attribute__((address_space(3))) unsigned int*)l,
        16, 0, 0);
}

// ---------------------------------------------------------------------------
// Kernel A (verbatim from verified R9/R0): 256 blocks x 32 rows. ||z_i||^2
// (fp32 exact), per-32-row min, z -> fp8 e4m3 (HW cvt_pk). Block 0 / wave 2:
// class counts over all s, analytic diagonal, out[0] = diag*scale.
// ---------------------------------------------------------------------------
__global__ __launch_bounds__(256) void dep_prep(
    const float* __restrict__ z, const int* __restrict__ s,
    float* __restrict__ sq, float* __restrict__ sqmin,
    unsigned char* __restrict__ zb8, float* __restrict__ pvals,
    const float* __restrict__ norm, float* __restrict__ out, int N)
{
    __shared__ float part[32][33];
    const int tid  = threadIdx.x;
    const int wave = tid >> 6, lane = tid & 63;
    const int half = lane >> 5, c = lane & 31;
    const int r0   = blockIdx.x * 32;

    if (blockIdx.x == 0 && wave == 2) {
        int c0 = 0, c1 = 0, c2 = 0, c3 = 0;
        for (int it = lane; it < N / 4; it += 64) {
            int4 v = ((const int4*)s)[it];
            c0 += (v.x == 0) + (v.y == 0) + (v.z == 0) + (v.w == 0);
            c1 += (v.x == 1) + (v.y == 1) + (v.z == 1) + (v.w == 1);
            c2 += (v.x == 2) + (v.y == 2) + (v.z == 2) + (v.w == 2);
            c3 += (v.x == 3) + (v.y == 3) + (v.z == 3) + (v.w == 3);
        }
        #pragma unroll
        for (int off = 1; off < 64; off <<= 1) {
            c0 += __shfl_xor(c0, off, 64);
            c1 += __shfl_xor(c1, off, 64);
            c2 += __shfl_xor(c2, off, 64);
            c3 += __shfl_xor(c3, off, 64);
        }
        if (lane == 0) {
            const double n = (double)N;
            const double p0 = c0 / n, p1 = c1 / n, p2 = c2 / n, p3 = c3 / n;
            const double sump2 = p0*p0 + p1*p1 + p2*p2 + p3*p3;
            const double scale = (1.0 - exp(-1.0)) / ((double)norm[0] * n * n);
            pvals[0] = (float)p0; pvals[1] = (float)p1;
            pvals[2] = (float)p2; pvals[3] = (float)p3;
            pvals[4] = (float)sump2;
            pvals[5] = (float)scale;
            const double c2sum = (double)c0*c0 + (double)c1*c1
                               + (double)c2*c2 + (double)c3*c3;
            const double diag = n - c2sum / n;   // K_z[i,i] = 1 analytically
            out[0] = (float)(diag * scale);
        }
    }

    #pragma unroll
    for (int i = 0; i < 4; ++i) {
        const int rloc = wave * 8 + i * 2 + half;
        const int r    = r0 + rloc;
        float4 v = ((const float4*)z)[r * 32 + c];
        int pk = __builtin_amdgcn_cvt_pk_fp8_f32(v.x, v.y, 0, false);
        pk     = __builtin_amdgcn_cvt_pk_fp8_f32(v.z, v.w, pk, true);
        ((unsigned int*)zb8)[r * 32 + c] = (unsigned int)pk;
        part[rloc][c] = v.x*v.x + v.y*v.y + v.z*v.z + v.w*v.w;
    }
    __syncthreads();

    if (wave == 0 && lane < 32) {
        float sum = 0.f;
        #pragma unroll
        for (int k = 0; k < 32; ++k) sum += part[lane][k];   // conflict-free
        sq[r0 + lane] = sum;
        float mn = sum;
        #pragma unroll
        for (int off = 1; off < 32; off <<= 1)               // lanes 0..31
            mn = fminf(mn, __shfl_xor(mn, off, 64));
        if (lane == 0) sqmin[blockIdx.x] = mn;
    }
}

// ---------------------------------------------------------------------------
// Kernel B: 256x256 super-tile, 8-WAVE blocks (512 thr). 528 blocks over the
// 32x32 super-triangle; 64 KB LDS; __launch_bounds__(512,4) -> 2 blocks/CU x
// 8 waves = 16 waves/CU (SAME TLP as the verified R0 128^2 kernel; R3's
// regression was 4-wave blocks halving TLP to 8/CU). vs R0: staged bytes
// 66.5 -> 33.8 MB, drain events 2080 -> 528, and 528 blocks ~ ONE co-resident
// round (512 slots) -> one drain per CU then pure compute. Wave w
// (wi = w>>1 in 0..3 selects 64-row A slice; qj = w&1) computes quadrant
// (wi&1, qj) of the two 128^2 sub-tiles b in {0,1}, sequentially (one accv,
// VGPR ~= R0). Panel layout, swizzle algebra, fragment path, bound + exact
// epilogue are verbatim R0 re-indexed (absmax-0 path).
// ---------------------------------------------------------------------------
__global__ __launch_bounds__(512, 4) void dep_pair(
    const unsigned char* __restrict__ zb8, const float* __restrict__ sq,
    const float* __restrict__ sqmin, const int* __restrict__ s,
    const float* __restrict__ pvals, float* __restrict__ out, int T)
{
    __shared__ unsigned char Apan[SPAN];   // 32KB (rows i0..i0+255)
    __shared__ unsigned char Bpan[SPAN];   // 32KB (rows j0..j0+255)

    const int tid  = threadIdx.x;
    const int wave = tid >> 6, lane = tid & 63;

    // block-uniform super-triangle map t -> (I <= J) over ST = T/2
    const int ST = T >> 1;
    const int t = blockIdx.x;
    #define TRI_BASE(x) ((x) * ST - ((x) * ((x) - 1)) / 2)
    double disc = (2.0 * ST + 1.0) * (2.0 * ST + 1.0) - 8.0 * (double)t;
    int I = (int)((2.0 * ST + 1.0 - sqrt(disc)) * 0.5);
    if (I < 0) I = 0;
    if (I > ST - 1) I = ST - 1;
    while (I + 1 < ST && TRI_BASE(I + 1) <= t) ++I;
    while (I > 0 && TRI_BASE(I) > t) --I;
    const int J = I + (t - TRI_BASE(I));
    #undef TRI_BASE

    const int i0 = I * 2 * BT, j0 = J * 2 * BT;   // super-tile origin rows
    const int wi = wave >> 1;                     // A 64-row slice (0..3)
    const int qj = wave & 1;                      // B quadrant within subtile
    const int l15 = lane & 15, quad = lane >> 4;

    // async stage both 256-row panels: per wave 4+4 DMAs of 1KB (8 rows).
    // Panel-local layout identical to R0: LDS[row][c] = G[row][c ^ (row&7)]
    {
        const int rl  = lane >> 3;          // row within 8-row group (0..7)
        const int cch = lane & 7;           // dest 16B-chunk within row
        const int gch = cch ^ rl;           // source chunk (row&7 == rl)
        #pragma unroll
        for (int k = 0; k < 4; ++k) {
            const int r0i = wave * 32 + k * 8;         // wave-uniform 0..255
            const size_t go = (size_t)(r0i + rl) * ZD + (gch << 4);
            async_copy16(zb8 + (size_t)i0 * ZD + go, Apan + r0i * ZD);
            async_copy16(zb8 + (size_t)j0 * ZD + go, Bpan + r0i * ZD);
        }
    }
    __syncthreads();   // single drain for all 64KB; one round -> one drain/CU

    const int sub = (quad & 1) * 8;         // 8B half within 16B chunk
    const int a   = wi >> 1;                // which 128-row subtile (A side)
    const int tis = 2 * I + a;

    #pragma unroll 1
    for (int b = 0; b < 2; ++b) {           // B-side 128-col subtile
        const int tjs = 2 * J + b;
        if (tis > tjs) continue;            // wave-uniform (only I==J, a=1,b=0)

        const int wjj = b * 2 + qj;         // B 64-row slice (0..3)

        f32x4 accv[4][4];
        #pragma unroll
        for (int x = 0; x < 4; ++x)
            #pragma unroll
            for (int y = 0; y < 4; ++y)
                accv[x][y] = (f32x4){0.f, 0.f, 0.f, 0.f};

        #pragma unroll
        for (int kc = 0; kc < 4; ++kc) {
            long af[4], bfr[4];
            // orig chunk = kc*2 + quad/2; row&7 == l15&7 for fragment rows
            const int ch = (kc * 2 + (quad >> 1)) ^ (l15 & 7);
            #pragma unroll
            for (int it = 0; it < 4; ++it) {
                const int row = wi * 64 + it * 16 + l15;
                af[it] = *(const long*)(Apan + row * ZD + (ch << 4) + sub);
            }
            #pragma unroll
            for (int jt = 0; jt < 4; ++jt) {
                const int row = wjj * 64 + jt * 16 + l15;
                bfr[jt] = *(const long*)(Bpan + row * ZD + (ch << 4) + sub);
            }
            #pragma unroll
            for (int it = 0; it < 4; ++it)
                #pragma unroll
                for (int jt = 0; jt < 4; ++jt)
                    accv[it][jt] = __builtin_amdgcn_mfma_f32_16x16x32_fp8_fp8(
                        af[it], bfr[jt], accv[it][jt], 0, 0, 0);
        }

        // ---- fast epilogue: wave-max dot vs conservative d2 lower bound ----
        float m = -1e30f;
        #pragma unroll
        for (int it = 0; it < 4; ++it)
            #pragma unroll
            for (int jt = 0; jt < 4; ++jt) {
                const f32x4 v = accv[it][jt];
                m = fmaxf(m, fmaxf(fmaxf(v[0], v[1]), fmaxf(v[2], v[3])));
            }
        #pragma unroll
        for (int off = 1; off < 64; off <<= 1)
            m = fmaxf(m, __shfl_xor(m, off, 64));

        const int ibase = i0 + wi * 64, jbase = j0 + wjj * 64;
        const int gA = ibase >> 5;                 // 32-row sqmin groups
        const int gB = jbase >> 5;
        const float sminA = fminf(sqmin[gA], sqmin[gA + 1]);
        const float sminB = fminf(sqmin[gB], sqmin[gB + 1]);
        const float bound = sminA + sminB - 2.0f * m;

        if (bound < D2_TRIG) {   // wave-uniform; diag quadrants + rare
            const float p0 = pvals[0], p1 = pvals[1],
                        p2 = pvals[2], p3 = pvals[3];
            const float sump2 = pvals[4], scale = pvals[5];
            const float p[4] = {p0, p1, p2, p3};

            float sqj[4];
            #pragma unroll
            for (int jt = 0; jt < 4; ++jt)
                sqj[jt] = sq[jbase + jt * 16 + l15];

            float local = 0.f;
            #pragma unroll
            for (int it = 0; it < 4; ++it) {
                #pragma unroll
                for (int r = 0; r < 4; ++r) {
                    const int i = ibase + it * 16 + quad * 4 + r;  // C/D row
                    const float sqi = sq[i];
                    #pragma unroll
                    for (int jt = 0; jt < 4; ++jt) {
                        const int j = jbase + jt * 16 + l15;       // C/D col
                        float d2 = sqi + sqj[jt] - 2.0f * accv[it][jt][r];
                        d2 = fmaxf(d2, 0.0f);
                        if (d2 < D2_CUT && i != j) {
                            const int si = s[i], sj = s[j];
                            const float w = (si == sj ? 1.0f : 0.0f)
                                          - p[si] - p[sj] + sump2;
                            local += w * __expf(-0.5f * d2);
                        }
                    }
                }
            }
            if (tis < tjs) local *= 2.0f;   // off-diag 128-tiles: both orders

            #pragma unroll
            for (int off = 32; off > 0; off >>= 1)
                local += __shfl_down(local, off, 64);
            if (lane == 0 && local != 0.0f)
                atomicAdd(out, local * scale);
        }
    }
}

extern "C" void kernel_launch(void* const* d_in, const int* in_sizes, int n_in,
                              void* d_out, int out_size, void* d_ws, size_t ws_size,
                              hipStream_t stream)
{
    const float* z    = (const float*)d_in[0];
    const int*   s    = (const int*)d_in[1];
    const float* norm = (const float*)d_in[2];
    float* out = (float*)d_out;

    const int N = in_sizes[1];       // 8192
    const int T = N / BT;            // 64 sub-tiles, 32 super-tiles

    char* ws = (char*)d_ws;
    float*         pvals = (float*)ws;                        // 6 floats @0
    float*         sq    = (float*)(ws + 64);                 // N floats
    float*         sqmin = (float*)(ws + 64 + (size_t)N * 4); // N/32
    unsigned char* zb8   = (unsigned char*)(ws + 64 + (size_t)N * 4
                                            + (size_t)(N / 32) * 4); // 16B-aligned

    dep_prep<<<N / 32, 256, 0, stream>>>(z, s, sq, sqmin, zb8, pvals,
                                         norm, out, N);
    const int ST = T / 2;
    const int nblocks = ST * (ST + 1) / 2;   // 528
    dep_pair<<<nblocks, 512, 0, stream>>>(zb8, sq, sqmin, s, pvals, out, T);
}

// Round 5
// 77.550 us; speedup vs baseline: 1.3137x; 1.0306x over previous
//
#include <hip/hip_runtime.h>

typedef float f32x4 __attribute__((ext_vector_type(4)));

#define ZD      128      // feature dim (bytes per fp8 row, too)
#define BTI     128      // tile rows (A side)
#define BTJ     64       // tile cols (B side)
#define D2_CUT  60.0f    // exact-path cutoff: exp(-30)~9e-14
#define D2_TRIG 70.0f    // trigger: fp8 dot err <= ~+-3 on d2 => skip implies
                         // true d2 >= 70-6 > D2_CUT (12-sigma data margin)

// async global->LDS DMA, 16B per lane; LDS dest = wave-uniform base + lane*16
__device__ __forceinline__ void async_copy16(const unsigned char* g,
                                             unsigned char* l) {
    __builtin_amdgcn_global_load_lds(
        (const __attribute__((address_space(1))) unsigned int*)g,
        (__attribute__((address_space(3))) unsigned int*)l,
        16, 0, 0);
}

// ---------------------------------------------------------------------------
// Kernel A: 1024 blocks x 8 rows (4 blocks/CU vs R0's 1 -- prep was
// latency-bound at 1 block/CU). ||z_i||^2 fp32-exact, per-8-row min,
// z -> fp8 e4m3 (HW cvt_pk). Block 0 / wave 2: class counts over all s,
// analytic diagonal, out[0] = diag*scale (identical double math to R0).
// ---------------------------------------------------------------------------
__global__ __launch_bounds__(256) void dep_prep(
    const float* __restrict__ z, const int* __restrict__ s,
    float* __restrict__ sq, float* __restrict__ sqmin8,
    unsigned char* __restrict__ zb8, float* __restrict__ pvals,
    const float* __restrict__ norm, float* __restrict__ out, int N)
{
    __shared__ float part[8][33];
    const int tid  = threadIdx.x;
    const int wave = tid >> 6, lane = tid & 63;
    const int half = lane >> 5, c = lane & 31;
    const int r0   = blockIdx.x * 8;

    if (blockIdx.x == 0 && wave == 2) {
        int c0 = 0, c1 = 0, c2 = 0, c3 = 0;
        for (int it = lane; it < N / 4; it += 64) {
            int4 v = ((const int4*)s)[it];
            c0 += (v.x == 0) + (v.y == 0) + (v.z == 0) + (v.w == 0);
            c1 += (v.x == 1) + (v.y == 1) + (v.z == 1) + (v.w == 1);
            c2 += (v.x == 2) + (v.y == 2) + (v.z == 2) + (v.w == 2);
            c3 += (v.x == 3) + (v.y == 3) + (v.z == 3) + (v.w == 3);
        }
        #pragma unroll
        for (int off = 1; off < 64; off <<= 1) {
            c0 += __shfl_xor(c0, off, 64);
            c1 += __shfl_xor(c1, off, 64);
            c2 += __shfl_xor(c2, off, 64);
            c3 += __shfl_xor(c3, off, 64);
        }
        if (lane == 0) {
            const double n = (double)N;
            const double p0 = c0 / n, p1 = c1 / n, p2 = c2 / n, p3 = c3 / n;
            const double sump2 = p0*p0 + p1*p1 + p2*p2 + p3*p3;
            const double scale = (1.0 - exp(-1.0)) / ((double)norm[0] * n * n);
            pvals[0] = (float)p0; pvals[1] = (float)p1;
            pvals[2] = (float)p2; pvals[3] = (float)p3;
            pvals[4] = (float)sump2;
            pvals[5] = (float)scale;
            const double c2sum = (double)c0*c0 + (double)c1*c1
                               + (double)c2*c2 + (double)c3*c3;
            const double diag = n - c2sum / n;   // K_z[i,i] = 1 analytically
            out[0] = (float)(diag * scale);
        }
    }

    {
        const int rloc = wave * 2 + half;        // 0..7
        const int r    = r0 + rloc;
        float4 v = ((const float4*)z)[r * 32 + c];
        int pk = __builtin_amdgcn_cvt_pk_fp8_f32(v.x, v.y, 0, false);
        pk     = __builtin_amdgcn_cvt_pk_fp8_f32(v.z, v.w, pk, true);
        ((unsigned int*)zb8)[r * 32 + c] = (unsigned int)pk;
        part[rloc][c] = v.x*v.x + v.y*v.y + v.z*v.z + v.w*v.w;
    }
    __syncthreads();

    if (wave == 0 && lane < 8) {
        float sum = 0.f;
        #pragma unroll
        for (int k = 0; k < 32; ++k) sum += part[lane][k];   // conflict-free
        sq[r0 + lane] = sum;
        float mn = sum;
        #pragma unroll
        for (int off = 1; off < 8; off <<= 1)                // lanes 0..7
            mn = fminf(mn, __shfl_xor(mn, off, 64));
        if (lane == 0) sqmin8[blockIdx.x] = mn;
    }
}

// ---------------------------------------------------------------------------
// Kernel B: 128x64 tiles, 64x32 wave-tiles (acc = 32 regs, HALF of R0) ->
// VGPR budget ~<=85 incl acc -> __launch_bounds__(256,6): 6 waves/SIMD.
// LDS 24 KB (A 16K + B 8K) -> 6 blocks/CU -> 24 waves/CU, 6-block stagger
// (R0: 16 waves / 4 blocks; R3/R4 showed both levers matter). Tiles
// (ti:128-row, tj2:64-col) with tj2 >= 2*ti cover the strict upper triangle;
// exact-path predicate j > i, UNCONDITIONAL x2 (each unordered pair counted
// once, doubled -- same total as R0's diag-tile-both-orders + off-diag-x2).
// Staging DMA layout/swizzle and fragment algebra verbatim R0 (B just has
// 2 jt sub-tiles instead of 4). Straddler tiles (tj2 in {2ti,2ti+1}) contain
// j<=i cells: their self-dots force the bound negative -> wave triggers ->
// exact path filters j > i. Output value unchanged -> absmax 0 preserved.
// ---------------------------------------------------------------------------
__global__ __launch_bounds__(256, 6) void dep_pair(
    const unsigned char* __restrict__ zb8, const float* __restrict__ sq,
    const float* __restrict__ sqmin8, const int* __restrict__ s,
    const float* __restrict__ pvals, float* __restrict__ out, int TJ)
{
    __shared__ unsigned char Apan[BTI * ZD];   // 16KB (128 rows)
    __shared__ unsigned char Bpan[BTJ * ZD];   // 8KB  (64 rows)

    const int tid  = threadIdx.x;
    const int wave = tid >> 6, lane = tid & 63;

    // block-uniform map t -> (ti, tj2) with tj2 >= 2*ti.
    // base(ti) = sum_{k<ti}(TJ-2k) = ti*(TJ+1-ti)
    const int t = blockIdx.x;
    #define TRI_BASE(x) ((x) * (TJ + 1 - (x)))
    const int TI = TJ >> 1;
    const float sf = sqrtf((float)((TJ + 1) * (TJ + 1) - 4 * t));
    int ti = (int)(((float)(TJ + 1) - sf) * 0.5f);
    if (ti < 0) ti = 0;
    if (ti > TI - 1) ti = TI - 1;
    while (ti + 1 < TI && TRI_BASE(ti + 1) <= t) ++ti;
    while (ti > 0 && TRI_BASE(ti) > t) --ti;
    const int tj2 = 2 * ti + (t - TRI_BASE(ti));
    #undef TRI_BASE

    const int i0 = ti * BTI, j0 = tj2 * BTJ;
    const int wi = wave >> 1;                 // A 64-row slice (0..1)
    const int wj = wave & 1;                  // B 32-row slice (0..1)
    const int l15 = lane & 15, quad = lane >> 4;

    // async stage panels: A 16 row-groups, B 8 row-groups over 4 waves.
    // Panel layout identical to R0: LDS[row][c] = G[row][c ^ (row&7)]
    {
        const int rl  = lane >> 3;          // row within 8-row group (0..7)
        const int cch = lane & 7;           // dest 16B-chunk within row
        const int gch = cch ^ rl;           // source chunk (row&7 == rl)
        const size_t goff = (size_t)rl * ZD + (gch << 4);
        const unsigned char* gAp = zb8 + (size_t)i0 * ZD;
        const unsigned char* gBp = zb8 + (size_t)j0 * ZD;
        #pragma unroll
        for (int k = 0; k < 4; ++k) {
            const int r0i = (wave * 4 + k) * 8;        // 0..127
            async_copy16(gAp + (size_t)r0i * ZD + goff, Apan + r0i * ZD);
        }
        #pragma unroll
        for (int k = 0; k < 2; ++k) {
            const int r0i = (wave * 2 + k) * 8;        // 0..63
            async_copy16(gBp + (size_t)r0i * ZD + goff, Bpan + r0i * ZD);
        }
    }
    __syncthreads();

    f32x4 accv[4][2];
    #pragma unroll
    for (int a = 0; a < 4; ++a)
        #pragma unroll
        for (int b = 0; b < 2; ++b)
            accv[a][b] = (f32x4){0.f, 0.f, 0.f, 0.f};

    const int sub = (quad & 1) * 8;         // 8B half within 16B chunk
    #pragma unroll
    for (int kc = 0; kc < 4; ++kc) {
        long af[4], bfr[2];
        // orig chunk = kc*2 + quad/2; row&7 == l15&7 for all fragment rows
        const int ch = (kc * 2 + (quad >> 1)) ^ (l15 & 7);
        #pragma unroll
        for (int it = 0; it < 4; ++it) {
            const int row = wi * 64 + it * 16 + l15;
            af[it] = *(const long*)(Apan + row * ZD + (ch << 4) + sub);
        }
        #pragma unroll
        for (int jt = 0; jt < 2; ++jt) {
            const int row = wj * 32 + jt * 16 + l15;
            bfr[jt] = *(const long*)(Bpan + row * ZD + (ch << 4) + sub);
        }
        #pragma unroll
        for (int it = 0; it < 4; ++it)
            #pragma unroll
            for (int jt = 0; jt < 2; ++jt)
                accv[it][jt] = __builtin_amdgcn_mfma_f32_16x16x32_fp8_fp8(
                    af[it], bfr[jt], accv[it][jt], 0, 0, 0);
    }

    // ---- fast epilogue: wave-max of dots vs conservative d2 lower bound ----
    float m = -1e30f;
    #pragma unroll
    for (int it = 0; it < 4; ++it)
        #pragma unroll
        for (int jt = 0; jt < 2; ++jt) {
            const f32x4 v = accv[it][jt];
            m = fmaxf(m, fmaxf(fmaxf(v[0], v[1]), fmaxf(v[2], v[3])));
        }
    #pragma unroll
    for (int off = 1; off < 64; off <<= 1)
        m = fmaxf(m, __shfl_xor(m, off, 64));

    const int ibase = i0 + wi * 64, jbase = j0 + wj * 32;
    const int gA = ibase >> 3;                 // 8-row sqmin groups
    const int gB = jbase >> 3;
    float sminA = sqmin8[gA];
    #pragma unroll
    for (int k = 1; k < 8; ++k) sminA = fminf(sminA, sqmin8[gA + k]);
    float sminB = sqmin8[gB];
    #pragma unroll
    for (int k = 1; k < 4; ++k) sminB = fminf(sminB, sqmin8[gB + k]);
    const float bound = sminA + sminB - 2.0f * m;

    if (bound < D2_TRIG) {   // wave-uniform; straddlers + rare triggers
        const float p0 = pvals[0], p1 = pvals[1],
                    p2 = pvals[2], p3 = pvals[3];
        const float sump2 = pvals[4], scale = pvals[5];
        const float p[4] = {p0, p1, p2, p3};

        float sqj[2];
        #pragma unroll
        for (int jt = 0; jt < 2; ++jt) sqj[jt] = sq[jbase + jt * 16 + l15];

        float local = 0.f;
        #pragma unroll
        for (int it = 0; it < 4; ++it) {
            #pragma unroll
            for (int r = 0; r < 4; ++r) {
                const int i = ibase + it * 16 + quad * 4 + r;  // C/D row
                const float sqi = sq[i];
                #pragma unroll
                for (int jt = 0; jt < 2; ++jt) {
                    const int j = jbase + jt * 16 + l15;       // C/D col
                    float d2 = sqi + sqj[jt] - 2.0f * accv[it][jt][r];
                    d2 = fmaxf(d2, 0.0f);
                    if (d2 < D2_CUT && j > i) {   // strict upper triangle
                        const int si = s[i], sj = s[j];
                        const float w = (si == sj ? 1.0f : 0.0f)
                                      - p[si] - p[sj] + sump2;
                        local += w * __expf(-0.5f * d2);
                    }
                }
            }
        }
        local *= 2.0f;   // each unordered pair counted once above

        #pragma unroll
        for (int off = 32; off > 0; off >>= 1)
            local += __shfl_down(local, off, 64);
        if (lane == 0 && local != 0.0f)
            atomicAdd(out, local * scale);
    }
}

extern "C" void kernel_launch(void* const* d_in, const int* in_sizes, int n_in,
                              void* d_out, int out_size, void* d_ws, size_t ws_size,
                              hipStream_t stream)
{
    const float* z    = (const float*)d_in[0];
    const int*   s    = (const int*)d_in[1];
    const float* norm = (const float*)d_in[2];
    float* out = (float*)d_out;

    const int N  = in_sizes[1];      // 8192
    const int TI = N / BTI;          // 64 row-tiles
    const int TJ = N / BTJ;          // 128 col-tiles

    char* ws = (char*)d_ws;
    float*         pvals  = (float*)ws;                        // 6 floats @0
    float*         sq     = (float*)(ws + 64);                 // N floats
    float*         sqmin8 = (float*)(ws + 64 + (size_t)N * 4); // N/8 floats
    unsigned char* zb8    = (unsigned char*)(ws + 64 + (size_t)N * 4
                                             + (size_t)(N / 8) * 4); // 16B-aligned

    dep_prep<<<N / 8, 256, 0, stream>>>(z, s, sq, sqmin8, zb8, pvals,
                                        norm, out, N);
    const int nblocks = TI * TJ - TI * (TI - 1);   // 4160
    dep_pair<<<nblocks, 256, 0, stream>>>(zb8, sq, sqmin8, s, pvals, out, TJ);
}